// Round 1
// baseline (792.506 us; speedup 1.0000x reference)
//
#include <hip/hip_runtime.h>
#include <cstdint>
#include <cstddef>

#define IN_C 128

static __device__ __forceinline__ float lrelu(float x) { return x > 0.f ? x : 0.2f * x; }

// ---------------- CSR build ----------------
__global__ void k_zero_i32(int* __restrict__ p, int n) {
  int i = blockIdx.x * 256 + threadIdx.x;
  if (i < n) p[i] = 0;
}

__global__ void k_count(const int* __restrict__ ei_dst, int* __restrict__ cnt, int E, int Et) {
  int e = blockIdx.x * 256 + threadIdx.x;
  if (e >= Et) return;
  int d = (e < E) ? ei_dst[e] : (e - E);
  atomicAdd(&cnt[d], 1);
}

__global__ void k_scan(const int* __restrict__ cnt, int* __restrict__ row_ptr,
                       int* __restrict__ fill, int n) {
  __shared__ int sdata[1024];
  __shared__ int s_run;
  int tid = threadIdx.x;
  if (tid == 0) s_run = 0;
  __syncthreads();
  for (int base = 0; base < n; base += 1024) {
    int i = base + tid;
    int v = (i < n) ? cnt[i] : 0;
    sdata[tid] = v;
    __syncthreads();
    for (int off = 1; off < 1024; off <<= 1) {
      int t = (tid >= off) ? sdata[tid - off] : 0;
      __syncthreads();
      sdata[tid] += t;
      __syncthreads();
    }
    int incl = sdata[tid];
    int run = s_run;
    if (i < n) { int excl = run + incl - v; row_ptr[i] = excl; fill[i] = excl; }
    __syncthreads();
    if (tid == 1023) s_run = run + incl;
    __syncthreads();
  }
  if (tid == 0) row_ptr[n] = s_run;
}

__global__ void k_scatter(const int* __restrict__ ei_src, const int* __restrict__ ei_dst,
                          int* __restrict__ fill, int* __restrict__ srcs, int E, int Et) {
  int e = blockIdx.x * 256 + threadIdx.x;
  if (e >= Et) return;
  int s, d;
  if (e < E) { s = ei_src[e]; d = ei_dst[e]; } else { s = e - E; d = s; }
  int pos = atomicAdd(&fill[d], 1);
  srcs[pos] = s;
}

// ---------------- fp32 tiled GEMM: C[M,N] = A[M,K] * B[K,N] ----------------
template <int BM, int BN, int BK>
__launch_bounds__(256)
__global__ void k_gemm(const float* __restrict__ A, const float* __restrict__ B,
                       float* __restrict__ C, int M, int N, int K) {
  __shared__ float As[BK][BM + 4];
  __shared__ float Bs[BK][BN + 4];
  int tid = threadIdx.x;
  int bm = blockIdx.x, bn = blockIdx.y;
  int rg = tid >> 4, cg = tid & 15;
  float acc[4][4] = {};
  for (int k0 = 0; k0 < K; k0 += BK) {
    // A tile: BM x BK, store transposed As[k][m]
#pragma unroll
    for (int it = 0; it < (BM * BK) / (256 * 4); ++it) {
      int idx = tid + it * 256;
      int row = idx / (BK / 4);
      int c4  = idx % (BK / 4);
      int m = bm * BM + row;
      float4 a = make_float4(0.f, 0.f, 0.f, 0.f);
      if (m < M) a = *(const float4*)&A[(size_t)m * K + k0 + c4 * 4];
      As[c4 * 4 + 0][row] = a.x;
      As[c4 * 4 + 1][row] = a.y;
      As[c4 * 4 + 2][row] = a.z;
      As[c4 * 4 + 3][row] = a.w;
    }
    // B tile: BK x BN, natural layout
#pragma unroll
    for (int it = 0; it < (BK * BN) / (256 * 4); ++it) {
      int idx = tid + it * 256;
      int row = idx / (BN / 4);
      int c4  = idx % (BN / 4);
      float4 b = *(const float4*)&B[(size_t)(k0 + row) * N + bn * BN + c4 * 4];
      *(float4*)&Bs[row][c4 * 4] = b;
    }
    __syncthreads();
#pragma unroll
    for (int kk = 0; kk < BK; ++kk) {
      float4 a4 = *(float4*)&As[kk][rg * 4];
      float4 b4 = *(float4*)&Bs[kk][cg * 4];
      float av[4] = {a4.x, a4.y, a4.z, a4.w};
      float bv[4] = {b4.x, b4.y, b4.z, b4.w};
#pragma unroll
      for (int i = 0; i < 4; ++i)
#pragma unroll
        for (int j = 0; j < 4; ++j) acc[i][j] += av[i] * bv[j];
    }
    __syncthreads();
  }
#pragma unroll
  for (int i = 0; i < 4; ++i) {
    int m = bm * BM + rg * 4 + i;
    if (m < M) {
      float4 o = make_float4(acc[i][0], acc[i][1], acc[i][2], acc[i][3]);
      *(float4*)&C[(size_t)m * N + bn * BN + cg * 4] = o;
    }
  }
}

// ---------------- alpha projections ----------------
__launch_bounds__(256)
__global__ void k_alpha1(const float* __restrict__ h1, const float* __restrict__ a_s,
                         const float* __restrict__ a_d, float* __restrict__ as,
                         float* __restrict__ ad, int n) {
  int wave = threadIdx.x >> 6, lane = threadIdx.x & 63;
  int node = blockIdx.x * 4 + wave;
  if (node >= n) return;
  float4 hv = *(const float4*)&h1[(size_t)node * 256 + lane * 4];
  float4 sv = *(const float4*)&a_s[lane * 4];
  float4 dv = *(const float4*)&a_d[lane * 4];
  float s = hv.x * sv.x + hv.y * sv.y + hv.z * sv.z + hv.w * sv.w;
  float d = hv.x * dv.x + hv.y * dv.y + hv.z * dv.z + hv.w * dv.w;
#pragma unroll
  for (int off = 1; off < 16; off <<= 1) { s += __shfl_xor(s, off); d += __shfl_xor(d, off); }
  if ((lane & 15) == 0) {
    as[node * 4 + (lane >> 4)] = s;
    ad[node * 4 + (lane >> 4)] = d;
  }
}

__launch_bounds__(256)
__global__ void k_alpha2(const float* __restrict__ h2, const float* __restrict__ a_s,
                         const float* __restrict__ a_d, float* __restrict__ as,
                         float* __restrict__ ad, int n) {
  int wave = threadIdx.x >> 6, lane = threadIdx.x & 63;
  int node = blockIdx.x * 4 + wave;
  if (node >= n) return;
  float hv = h2[(size_t)node * 64 + lane];
  float s = hv * a_s[lane];
  float d = hv * a_d[lane];
#pragma unroll
  for (int off = 1; off < 64; off <<= 1) { s += __shfl_xor(s, off); d += __shfl_xor(d, off); }
  if (lane == 0) { as[node] = s; ad[node] = d; }
}

// ---------------- per-dst aggregation, layer 1 (4 heads x 64 ch) ----------------
__launch_bounds__(256)
__global__ void k_aggr1(const int* __restrict__ row_ptr, const int* __restrict__ srcs,
                        const float* __restrict__ as1, const float* __restrict__ ad1,
                        const float* __restrict__ h1, const float* __restrict__ b1,
                        float* __restrict__ hrelu, int n) {
  int wave = threadIdx.x >> 6, lane = threadIdx.x & 63;
  int node = blockIdx.x * 4 + wave;
  if (node >= n) return;
  int beg = row_ptr[node], end = row_ptr[node + 1];
  float4 adv = *(const float4*)&ad1[node * 4];
  // pass A: per-head max (lane-parallel over edges)
  float m0 = -1e30f, m1 = -1e30f, m2 = -1e30f, m3 = -1e30f;
  for (int i = beg + lane; i < end; i += 64) {
    int s = srcs[i];
    float4 asv = *(const float4*)&as1[s * 4];
    m0 = fmaxf(m0, lrelu(asv.x + adv.x));
    m1 = fmaxf(m1, lrelu(asv.y + adv.y));
    m2 = fmaxf(m2, lrelu(asv.z + adv.z));
    m3 = fmaxf(m3, lrelu(asv.w + adv.w));
  }
#pragma unroll
  for (int off = 1; off < 64; off <<= 1) {
    m0 = fmaxf(m0, __shfl_xor(m0, off));
    m1 = fmaxf(m1, __shfl_xor(m1, off));
    m2 = fmaxf(m2, __shfl_xor(m2, off));
    m3 = fmaxf(m3, __shfl_xor(m3, off));
  }
  // pass B: per-head sum of exp
  float d0 = 0, d1 = 0, d2 = 0, d3 = 0;
  for (int i = beg + lane; i < end; i += 64) {
    int s = srcs[i];
    float4 asv = *(const float4*)&as1[s * 4];
    d0 += __expf(lrelu(asv.x + adv.x) - m0);
    d1 += __expf(lrelu(asv.y + adv.y) - m1);
    d2 += __expf(lrelu(asv.z + adv.z) - m2);
    d3 += __expf(lrelu(asv.w + adv.w) - m3);
  }
#pragma unroll
  for (int off = 1; off < 64; off <<= 1) {
    d0 += __shfl_xor(d0, off); d1 += __shfl_xor(d1, off);
    d2 += __shfl_xor(d2, off); d3 += __shfl_xor(d3, off);
  }
  // per-lane head selection (lane>>4), static selects to stay in registers
  int hi16 = lane & 16, hi32 = lane & 32;
  float admy = hi32 ? (hi16 ? adv.w : adv.z) : (hi16 ? adv.y : adv.x);
  float mmy  = hi32 ? (hi16 ? m3 : m2) : (hi16 ? m1 : m0);
  float dmy  = hi32 ? (hi16 ? d3 : d2) : (hi16 ? d1 : d0);
  float inv = 1.0f / (dmy + 1e-16f);
  int myh = lane >> 4;
  // pass C: whole-wave gather of h1[src] (1KB/edge), weighted accumulate
  float ax = 0, ay = 0, az = 0, aw = 0;
  for (int i = beg; i < end; ++i) {
    int s = srcs[i];
    float e = lrelu(as1[s * 4 + myh] + admy);
    float w = __expf(e - mmy) * inv;
    float4 hv = *(const float4*)&h1[(size_t)s * 256 + lane * 4];
    ax += w * hv.x; ay += w * hv.y; az += w * hv.z; aw += w * hv.w;
  }
  float4 bv = *(const float4*)&b1[lane * 4];
  float4 o;
  o.x = fmaxf(ax + bv.x, 0.f);
  o.y = fmaxf(ay + bv.y, 0.f);
  o.z = fmaxf(az + bv.z, 0.f);
  o.w = fmaxf(aw + bv.w, 0.f);
  *(float4*)&hrelu[(size_t)node * 256 + lane * 4] = o;
}

// ---------------- per-dst aggregation, layer 2 (1 head x 64 ch) ----------------
__launch_bounds__(256)
__global__ void k_aggr2(const int* __restrict__ row_ptr, const int* __restrict__ srcs,
                        const float* __restrict__ as2, const float* __restrict__ ad2,
                        const float* __restrict__ h2, const float* __restrict__ b2,
                        float* __restrict__ out, int n) {
  int wave = threadIdx.x >> 6, lane = threadIdx.x & 63;
  int node = blockIdx.x * 4 + wave;
  if (node >= n) return;
  int beg = row_ptr[node], end = row_ptr[node + 1];
  float adm = ad2[node];
  float mx = -1e30f;
  for (int i = beg + lane; i < end; i += 64)
    mx = fmaxf(mx, lrelu(as2[srcs[i]] + adm));
#pragma unroll
  for (int off = 1; off < 64; off <<= 1) mx = fmaxf(mx, __shfl_xor(mx, off));
  float den = 0;
  for (int i = beg + lane; i < end; i += 64)
    den += __expf(lrelu(as2[srcs[i]] + adm) - mx);
#pragma unroll
  for (int off = 1; off < 64; off <<= 1) den += __shfl_xor(den, off);
  float inv = 1.0f / (den + 1e-16f);
  float acc = 0;
  for (int i = beg; i < end; ++i) {
    int s = srcs[i];
    float w = __expf(lrelu(as2[s] + adm) - mx) * inv;
    acc += w * h2[(size_t)s * 64 + lane];
  }
  out[(size_t)node * 64 + lane] = acc + b2[lane];
}

// ---------------- launch ----------------
extern "C" void kernel_launch(void* const* d_in, const int* in_sizes, int n_in,
                              void* d_out, int out_size, void* d_ws, size_t ws_size,
                              hipStream_t stream) {
  const float* x    = (const float*)d_in[0];
  const int*   ei   = (const int*)d_in[1];
  const float* W1   = (const float*)d_in[2];
  const float* a_s1 = (const float*)d_in[3];
  const float* a_d1 = (const float*)d_in[4];
  const float* b1   = (const float*)d_in[5];
  const float* W2   = (const float*)d_in[6];
  const float* a_s2 = (const float*)d_in[7];
  const float* a_d2 = (const float*)d_in[8];
  const float* b2   = (const float*)d_in[9];
  float* out = (float*)d_out;

  const int n  = in_sizes[0] / IN_C;  // 50000
  const int E  = in_sizes[1] / 2;     // 1600000
  const int Et = E + n;
  const int* ei_src = ei;
  const int* ei_dst = ei + E;

  char* ws = (char*)d_ws;
  size_t off = 0;
  auto alloc = [&](size_t bytes) -> void* {
    void* p = ws + off;
    off = (off + bytes + 255) & ~(size_t)255;
    return p;
  };
  float* h1    = (float*)alloc((size_t)n * 256 * 4);
  float* hrelu = (float*)alloc((size_t)n * 256 * 4);
  float* h2    = (float*)alloc((size_t)n * 64 * 4);
  float* as1   = (float*)alloc((size_t)n * 4 * 4);
  float* ad1   = (float*)alloc((size_t)n * 4 * 4);
  float* as2   = (float*)alloc((size_t)n * 4);
  float* ad2   = (float*)alloc((size_t)n * 4);
  int* cnt     = (int*)alloc((size_t)n * 4);
  int* row_ptr = (int*)alloc((size_t)(n + 1) * 4);
  int* fill    = (int*)alloc((size_t)n * 4);
  int* srcs    = (int*)alloc((size_t)Et * 4);

  int eb = (Et + 255) / 256;
  int nb = (n + 255) / 256;
  int nw = (n + 3) / 4;

  hipLaunchKernelGGL(k_zero_i32, dim3(nb), dim3(256), 0, stream, cnt, n);
  hipLaunchKernelGGL(k_count, dim3(eb), dim3(256), 0, stream, ei_dst, cnt, E, Et);
  hipLaunchKernelGGL(k_scan, dim3(1), dim3(1024), 0, stream, cnt, row_ptr, fill, n);
  hipLaunchKernelGGL(k_scatter, dim3(eb), dim3(256), 0, stream, ei_src, ei_dst, fill, srcs, E, Et);

  hipLaunchKernelGGL((k_gemm<64, 64, 32>), dim3((n + 63) / 64, 4), dim3(256), 0, stream,
                     x, W1, h1, n, 256, 128);
  hipLaunchKernelGGL(k_alpha1, dim3(nw), dim3(256), 0, stream, h1, a_s1, a_d1, as1, ad1, n);
  hipLaunchKernelGGL(k_aggr1, dim3(nw), dim3(256), 0, stream, row_ptr, srcs, as1, ad1, h1, b1, hrelu, n);
  hipLaunchKernelGGL((k_gemm<64, 64, 32>), dim3((n + 63) / 64, 1), dim3(256), 0, stream,
                     hrelu, W2, h2, n, 64, 256);
  hipLaunchKernelGGL(k_alpha2, dim3(nw), dim3(256), 0, stream, h2, a_s2, a_d2, as2, ad2, n);
  hipLaunchKernelGGL(k_aggr2, dim3(nw), dim3(256), 0, stream, row_ptr, srcs, as2, ad2, h2, b2, out, n);
}

// Round 2
// 547.094 us; speedup vs baseline: 1.4486x; 1.4486x over previous
//
#include <hip/hip_runtime.h>
#include <cstdint>
#include <cstddef>

#define IN_C 128

typedef _Float16 __attribute__((ext_vector_type(2))) half2v;
typedef _Float16 __attribute__((ext_vector_type(4))) half4v;
typedef _Float16 __attribute__((ext_vector_type(8))) half8v;

static __device__ __forceinline__ float lrelu(float x) { return x > 0.f ? x : 0.2f * x; }

// ---------------- CSR build ----------------
__global__ void k_zero_i32(int* __restrict__ p, int n) {
  int i = blockIdx.x * 256 + threadIdx.x;
  if (i < n) p[i] = 0;
}

__global__ void k_count(const int* __restrict__ ei_dst, int* __restrict__ cnt, int E, int Et) {
  int e = blockIdx.x * 256 + threadIdx.x;
  if (e >= Et) return;
  int d = (e < E) ? ei_dst[e] : (e - E);
  atomicAdd(&cnt[d], 1);
}

// hierarchical scan: per-block local exclusive scan + block sums
__global__ void k_scan1(const int* __restrict__ cnt, int* __restrict__ loc,
                        int* __restrict__ bsum, int n) {
  int tid = threadIdx.x;
  int i = blockIdx.x * 256 + tid;
  int v = (i < n) ? cnt[i] : 0;
  int lane = tid & 63, w = tid >> 6;
  int s = v;
#pragma unroll
  for (int off = 1; off < 64; off <<= 1) {
    int t = __shfl_up(s, off);
    if (lane >= off) s += t;
  }
  __shared__ int wt[4];
  if (lane == 63) wt[w] = s;
  __syncthreads();
  int add = 0;
#pragma unroll
  for (int k = 0; k < 4; ++k)
    if (k < w) add += wt[k];
  int incl = s + add;
  if (i < n) loc[i] = incl - v;
  if (tid == 255) bsum[blockIdx.x] = incl;
}

__global__ void k_scan2(int* __restrict__ bsum, int nb, int* __restrict__ total_out) {
  int tid = threadIdx.x;
  int v = (tid < nb) ? bsum[tid] : 0;
  int lane = tid & 63, w = tid >> 6;
  int s = v;
#pragma unroll
  for (int off = 1; off < 64; off <<= 1) {
    int t = __shfl_up(s, off);
    if (lane >= off) s += t;
  }
  __shared__ int wt[4];
  if (lane == 63) wt[w] = s;
  __syncthreads();
  int add = 0;
#pragma unroll
  for (int k = 0; k < 4; ++k)
    if (k < w) add += wt[k];
  int incl = s + add;
  if (tid < nb) bsum[tid] = incl - v;  // exclusive
  if (tid == 255) *total_out = incl;   // grand total -> row_ptr[n]
}

__global__ void k_scan3(const int* __restrict__ loc, const int* __restrict__ bsum,
                        int* __restrict__ row_ptr, int* __restrict__ fill, int n) {
  int i = blockIdx.x * 256 + threadIdx.x;
  if (i < n) {
    int v = loc[i] + bsum[blockIdx.x];
    row_ptr[i] = v;
    fill[i] = v;
  }
}

__global__ void k_scatter(const int* __restrict__ ei_src, const int* __restrict__ ei_dst,
                          int* __restrict__ fill, int* __restrict__ srcs, int E, int Et) {
  int e = blockIdx.x * 256 + threadIdx.x;
  if (e >= Et) return;
  int s, d;
  if (e < E) { s = ei_src[e]; d = ei_dst[e]; } else { s = e - E; d = s; }
  int pos = atomicAdd(&fill[d], 1);
  srcs[pos] = s;
}

// ---------------- fp32 tiled GEMM, fp16 output: C[M,N] = A[M,K] * B[K,N] ----------------
template <int BM, int BN, int BK>
__launch_bounds__(256)
__global__ void k_gemm_h(const float* __restrict__ A, const float* __restrict__ B,
                         _Float16* __restrict__ C, int M, int N, int K) {
  __shared__ float As[BK][BM + 4];
  __shared__ float Bs[BK][BN + 4];
  int tid = threadIdx.x;
  int bm = blockIdx.x, bn = blockIdx.y;
  int rg = tid >> 4, cg = tid & 15;
  float acc[4][4] = {};
  for (int k0 = 0; k0 < K; k0 += BK) {
#pragma unroll
    for (int it = 0; it < (BM * BK) / (256 * 4); ++it) {
      int idx = tid + it * 256;
      int row = idx / (BK / 4);
      int c4  = idx % (BK / 4);
      int m = bm * BM + row;
      float4 a = make_float4(0.f, 0.f, 0.f, 0.f);
      if (m < M) a = *(const float4*)&A[(size_t)m * K + k0 + c4 * 4];
      As[c4 * 4 + 0][row] = a.x;
      As[c4 * 4 + 1][row] = a.y;
      As[c4 * 4 + 2][row] = a.z;
      As[c4 * 4 + 3][row] = a.w;
    }
#pragma unroll
    for (int it = 0; it < (BK * BN) / (256 * 4); ++it) {
      int idx = tid + it * 256;
      int row = idx / (BN / 4);
      int c4  = idx % (BN / 4);
      float4 b = *(const float4*)&B[(size_t)(k0 + row) * N + bn * BN + c4 * 4];
      *(float4*)&Bs[row][c4 * 4] = b;
    }
    __syncthreads();
#pragma unroll
    for (int kk = 0; kk < BK; ++kk) {
      float4 a4 = *(float4*)&As[kk][rg * 4];
      float4 b4 = *(float4*)&Bs[kk][cg * 4];
      float av[4] = {a4.x, a4.y, a4.z, a4.w};
      float bv[4] = {b4.x, b4.y, b4.z, b4.w};
#pragma unroll
      for (int i = 0; i < 4; ++i)
#pragma unroll
        for (int j = 0; j < 4; ++j) acc[i][j] += av[i] * bv[j];
    }
    __syncthreads();
  }
#pragma unroll
  for (int i = 0; i < 4; ++i) {
    int m = bm * BM + rg * 4 + i;
    if (m < M) {
      half4v o;
      o.x = (_Float16)acc[i][0];
      o.y = (_Float16)acc[i][1];
      o.z = (_Float16)acc[i][2];
      o.w = (_Float16)acc[i][3];
      *(half4v*)&C[(size_t)m * N + bn * BN + cg * 4] = o;
    }
  }
}

// ---------------- alpha projections ----------------
__launch_bounds__(256)
__global__ void k_alpha1(const _Float16* __restrict__ h1h, const float* __restrict__ a_s,
                         const float* __restrict__ a_d, float* __restrict__ as,
                         float* __restrict__ ad, int n) {
  int wave = threadIdx.x >> 6, lane = threadIdx.x & 63;
  int node = blockIdx.x * 4 + wave;
  if (node >= n) return;
  half4v hv = *(const half4v*)&h1h[(size_t)node * 256 + lane * 4];
  float4 sv = *(const float4*)&a_s[lane * 4];
  float4 dv = *(const float4*)&a_d[lane * 4];
  float h0 = (float)hv.x, h1 = (float)hv.y, h2 = (float)hv.z, h3 = (float)hv.w;
  float s = h0 * sv.x + h1 * sv.y + h2 * sv.z + h3 * sv.w;
  float d = h0 * dv.x + h1 * dv.y + h2 * dv.z + h3 * dv.w;
#pragma unroll
  for (int off = 1; off < 16; off <<= 1) { s += __shfl_xor(s, off); d += __shfl_xor(d, off); }
  if ((lane & 15) == 0) {
    as[node * 4 + (lane >> 4)] = s;
    ad[node * 4 + (lane >> 4)] = d;
  }
}

__launch_bounds__(256)
__global__ void k_alpha2(const _Float16* __restrict__ h2h, const float* __restrict__ a_s,
                         const float* __restrict__ a_d, float* __restrict__ as,
                         float* __restrict__ ad, int n) {
  int wave = threadIdx.x >> 6, lane = threadIdx.x & 63;
  int node = blockIdx.x * 4 + wave;
  if (node >= n) return;
  float hv = (float)h2h[(size_t)node * 64 + lane];
  float s = hv * a_s[lane];
  float d = hv * a_d[lane];
#pragma unroll
  for (int off = 1; off < 64; off <<= 1) { s += __shfl_xor(s, off); d += __shfl_xor(d, off); }
  if (lane == 0) { as[node] = s; ad[node] = d; }
}

// ---------------- aggregation, layer 1 (4 heads x 64 ch), fp16 gather ----------------
__launch_bounds__(256)
__global__ void k_aggr1(const int* __restrict__ row_ptr, const int* __restrict__ srcs,
                        const float* __restrict__ as1, const float* __restrict__ ad1,
                        const _Float16* __restrict__ h1h, const float* __restrict__ b1,
                        float* __restrict__ hrelu, int n) {
  int wave = threadIdx.x >> 6, lane = threadIdx.x & 63;
  int node = blockIdx.x * 4 + wave;
  if (node >= n) return;
  int beg = row_ptr[node], end = row_ptr[node + 1];
  float4 adv = *(const float4*)&ad1[node * 4];
  // denominator pass (softmax is shift-invariant; logits bounded, no max pass)
  float d0 = 0, d1 = 0, d2 = 0, d3 = 0;
  for (int i = beg + lane; i < end; i += 64) {
    int s = srcs[i];
    float4 asv = *(const float4*)&as1[s * 4];
    d0 += __expf(lrelu(asv.x + adv.x));
    d1 += __expf(lrelu(asv.y + adv.y));
    d2 += __expf(lrelu(asv.z + adv.z));
    d3 += __expf(lrelu(asv.w + adv.w));
  }
#pragma unroll
  for (int off = 1; off < 64; off <<= 1) {
    d0 += __shfl_xor(d0, off); d1 += __shfl_xor(d1, off);
    d2 += __shfl_xor(d2, off); d3 += __shfl_xor(d3, off);
  }
  // gather pass: 2 edges/iter; lanes 0-31 -> edge i, lanes 32-63 -> edge i+1
  int l32 = lane & 31, sub = lane >> 5;
  int ch0 = l32 * 8;        // channel base 0..248
  int myh = l32 >> 3;       // head 0..3
  float admy = (myh & 2) ? ((myh & 1) ? adv.w : adv.z) : ((myh & 1) ? adv.y : adv.x);
  float dmy  = (myh & 2) ? ((myh & 1) ? d3 : d2) : ((myh & 1) ? d1 : d0);
  float inv = 1.0f / (dmy + 1e-16f);
  float acc[8] = {};
  for (int i = beg; i < end; i += 2) {
    int idx = i + sub;
    float w = 0.f;
    int s = 0;
    if (idx < end) {
      s = srcs[idx];
      w = __expf(lrelu(as1[s * 4 + myh] + admy)) * inv;
    }
    half8v hv = *(const half8v*)&h1h[(size_t)s * 256 + ch0];
#pragma unroll
    for (int j = 0; j < 8; ++j) acc[j] += w * (float)hv[j];
  }
#pragma unroll
  for (int j = 0; j < 8; ++j) acc[j] += __shfl_xor(acc[j], 32);
  if (sub == 0) {
#pragma unroll
    for (int j = 0; j < 8; ++j) acc[j] = fmaxf(acc[j] + b1[ch0 + j], 0.f);
    *(float4*)&hrelu[(size_t)node * 256 + ch0]     = make_float4(acc[0], acc[1], acc[2], acc[3]);
    *(float4*)&hrelu[(size_t)node * 256 + ch0 + 4] = make_float4(acc[4], acc[5], acc[6], acc[7]);
  }
}

// ---------------- aggregation, layer 2 (1 head x 64 ch), fp16 gather ----------------
__launch_bounds__(256)
__global__ void k_aggr2(const int* __restrict__ row_ptr, const int* __restrict__ srcs,
                        const float* __restrict__ as2, const float* __restrict__ ad2,
                        const _Float16* __restrict__ h2h, const float* __restrict__ b2,
                        float* __restrict__ out, int n) {
  int wave = threadIdx.x >> 6, lane = threadIdx.x & 63;
  int node = blockIdx.x * 4 + wave;
  if (node >= n) return;
  int beg = row_ptr[node], end = row_ptr[node + 1];
  float adm = ad2[node];
  float den = 0;
  for (int i = beg + lane; i < end; i += 64)
    den += __expf(lrelu(as2[srcs[i]] + adm));
#pragma unroll
  for (int off = 1; off < 64; off <<= 1) den += __shfl_xor(den, off);
  float inv = 1.0f / (den + 1e-16f);
  int l32 = lane & 31, sub = lane >> 5;
  int ch0 = l32 * 2;
  float a0 = 0.f, a1 = 0.f;
  for (int i = beg; i < end; i += 2) {
    int idx = i + sub;
    float w = 0.f;
    int s = 0;
    if (idx < end) {
      s = srcs[idx];
      w = __expf(lrelu(as2[s] + adm)) * inv;
    }
    half2v hv = *(const half2v*)&h2h[(size_t)s * 64 + ch0];
    a0 += w * (float)hv.x;
    a1 += w * (float)hv.y;
  }
  a0 += __shfl_xor(a0, 32);
  a1 += __shfl_xor(a1, 32);
  if (sub == 0) {
    float2 o;
    o.x = a0 + b2[ch0];
    o.y = a1 + b2[ch0 + 1];
    *(float2*)&out[(size_t)node * 64 + ch0] = o;
  }
}

// ---------------- launch ----------------
extern "C" void kernel_launch(void* const* d_in, const int* in_sizes, int n_in,
                              void* d_out, int out_size, void* d_ws, size_t ws_size,
                              hipStream_t stream) {
  const float* x    = (const float*)d_in[0];
  const int*   ei   = (const int*)d_in[1];
  const float* W1   = (const float*)d_in[2];
  const float* a_s1 = (const float*)d_in[3];
  const float* a_d1 = (const float*)d_in[4];
  const float* b1   = (const float*)d_in[5];
  const float* W2   = (const float*)d_in[6];
  const float* a_s2 = (const float*)d_in[7];
  const float* a_d2 = (const float*)d_in[8];
  const float* b2   = (const float*)d_in[9];
  float* out = (float*)d_out;

  const int n  = in_sizes[0] / IN_C;  // 50000
  const int E  = in_sizes[1] / 2;     // 1600000
  const int Et = E + n;
  const int* ei_src = ei;
  const int* ei_dst = ei + E;

  char* ws = (char*)d_ws;
  size_t off = 0;
  auto alloc = [&](size_t bytes) -> void* {
    void* p = ws + off;
    off = (off + bytes + 255) & ~(size_t)255;
    return p;
  };
  _Float16* h1h  = (_Float16*)alloc((size_t)n * 256 * 2);
  float* hrelu   = (float*)alloc((size_t)n * 256 * 4);
  _Float16* h2h  = (_Float16*)alloc((size_t)n * 64 * 2);
  float* as1     = (float*)alloc((size_t)n * 4 * 4);
  float* ad1     = (float*)alloc((size_t)n * 4 * 4);
  float* as2     = (float*)alloc((size_t)n * 4);
  float* ad2     = (float*)alloc((size_t)n * 4);
  int* cnt       = (int*)alloc((size_t)n * 4);
  int* loc       = (int*)alloc((size_t)n * 4);
  int* row_ptr   = (int*)alloc((size_t)(n + 1) * 4);
  int* fill      = (int*)alloc((size_t)n * 4);
  int* bsum      = (int*)alloc((size_t)256 * 4);
  int* srcs      = (int*)alloc((size_t)Et * 4);

  int eb  = (Et + 255) / 256;
  int nb  = (n + 255) / 256;
  int nw  = (n + 3) / 4;

  hipLaunchKernelGGL(k_zero_i32, dim3(nb), dim3(256), 0, stream, cnt, n);
  hipLaunchKernelGGL(k_count, dim3(eb), dim3(256), 0, stream, ei_dst, cnt, E, Et);
  hipLaunchKernelGGL(k_scan1, dim3(nb), dim3(256), 0, stream, cnt, loc, bsum, n);
  hipLaunchKernelGGL(k_scan2, dim3(1), dim3(256), 0, stream, bsum, nb, row_ptr + n);
  hipLaunchKernelGGL(k_scan3, dim3(nb), dim3(256), 0, stream, loc, bsum, row_ptr, fill, n);
  hipLaunchKernelGGL(k_scatter, dim3(eb), dim3(256), 0, stream, ei_src, ei_dst, fill, srcs, E, Et);

  hipLaunchKernelGGL((k_gemm_h<64, 64, 32>), dim3((n + 63) / 64, 4), dim3(256), 0, stream,
                     x, W1, h1h, n, 256, 128);
  hipLaunchKernelGGL(k_alpha1, dim3(nw), dim3(256), 0, stream, h1h, a_s1, a_d1, as1, ad1, n);
  hipLaunchKernelGGL(k_aggr1, dim3(nw), dim3(256), 0, stream, row_ptr, srcs, as1, ad1, h1h, b1, hrelu, n);
  hipLaunchKernelGGL((k_gemm_h<64, 64, 32>), dim3((n + 63) / 64, 1), dim3(256), 0, stream,
                     hrelu, W2, h2h, n, 64, 256);
  hipLaunchKernelGGL(k_alpha2, dim3(nw), dim3(256), 0, stream, h2h, a_s2, a_d2, as2, ad2, n);
  hipLaunchKernelGGL(k_aggr2, dim3(nw), dim3(256), 0, stream, row_ptr, srcs, as2, ad2, h2h, b2, out, n);
}

// Round 3
// 493.596 us; speedup vs baseline: 1.6056x; 1.1084x over previous
//
#include <hip/hip_runtime.h>
#include <cstdint>
#include <cstddef>

#define IN_C 128

typedef _Float16 __attribute__((ext_vector_type(4))) half4v;
typedef _Float16 __attribute__((ext_vector_type(8))) f16x8;
typedef float    __attribute__((ext_vector_type(4))) f32x4;

static __device__ __forceinline__ float lrelu(float x) { return x > 0.f ? x : 0.2f * x; }

static __device__ __forceinline__ float pick_h4(uint2 w, int myh) {
  unsigned s = (myh & 2) ? w.y : w.x;
  unsigned short b = (myh & 1) ? (unsigned short)(s >> 16) : (unsigned short)(s & 0xffffu);
  union { unsigned short u; _Float16 h; } c; c.u = b;
  return (float)c.h;
}

// ---------------- CSR build ----------------
__global__ void k_zero_i32(int* __restrict__ p, int n) {
  int i = blockIdx.x * 256 + threadIdx.x;
  if (i < n) p[i] = 0;
}

__global__ void k_count(const int* __restrict__ ei_dst, int* __restrict__ cnt, int E, int Et) {
  int e = blockIdx.x * 256 + threadIdx.x;
  if (e >= Et) return;
  int d = (e < E) ? ei_dst[e] : (e - E);
  atomicAdd(&cnt[d], 1);
}

__global__ void k_scan1(const int* __restrict__ cnt, int* __restrict__ loc,
                        int* __restrict__ bsum, int n) {
  int tid = threadIdx.x;
  int i = blockIdx.x * 256 + tid;
  int v = (i < n) ? cnt[i] : 0;
  int lane = tid & 63, w = tid >> 6;
  int s = v;
#pragma unroll
  for (int off = 1; off < 64; off <<= 1) {
    int t = __shfl_up(s, off);
    if (lane >= off) s += t;
  }
  __shared__ int wt[4];
  if (lane == 63) wt[w] = s;
  __syncthreads();
  int add = 0;
#pragma unroll
  for (int k = 0; k < 4; ++k)
    if (k < w) add += wt[k];
  int incl = s + add;
  if (i < n) loc[i] = incl - v;
  if (tid == 255) bsum[blockIdx.x] = incl;
}

__global__ void k_scan2(int* __restrict__ bsum, int nb, int* __restrict__ total_out) {
  int tid = threadIdx.x;
  int v = (tid < nb) ? bsum[tid] : 0;
  int lane = tid & 63, w = tid >> 6;
  int s = v;
#pragma unroll
  for (int off = 1; off < 64; off <<= 1) {
    int t = __shfl_up(s, off);
    if (lane >= off) s += t;
  }
  __shared__ int wt[4];
  if (lane == 63) wt[w] = s;
  __syncthreads();
  int add = 0;
#pragma unroll
  for (int k = 0; k < 4; ++k)
    if (k < w) add += wt[k];
  int incl = s + add;
  if (tid < nb) bsum[tid] = incl - v;
  if (tid == 255) *total_out = incl;
}

__global__ void k_scan3(const int* __restrict__ loc, const int* __restrict__ bsum,
                        int* __restrict__ row_ptr, int* __restrict__ fill, int n) {
  int i = blockIdx.x * 256 + threadIdx.x;
  if (i < n) {
    int v = loc[i] + bsum[blockIdx.x];
    row_ptr[i] = v;
    fill[i] = v;
  }
}

__global__ void k_scatter(const int* __restrict__ ei_src, const int* __restrict__ ei_dst,
                          int* __restrict__ fill, int* __restrict__ srcs,
                          int* __restrict__ dsts, int E, int Et) {
  int e = blockIdx.x * 256 + threadIdx.x;
  if (e >= Et) return;
  int s, d;
  if (e < E) { s = ei_src[e]; d = ei_dst[e]; } else { s = e - E; d = s; }
  int pos = atomicAdd(&fill[d], 1);
  srcs[pos] = s;
  dsts[pos] = d;
}

// ---------------- prep: casts / transposes ----------------
__global__ void k_xh(const float* __restrict__ x, _Float16* __restrict__ xh, int n4) {
  int i = blockIdx.x * 256 + threadIdx.x;
  if (i >= n4) return;
  float4 v = *(const float4*)&x[i * 4];
  half4v o;
  o.x = (_Float16)v.x; o.y = (_Float16)v.y; o.z = (_Float16)v.z; o.w = (_Float16)v.w;
  *(half4v*)&xh[i * 4] = o;
}

// W [K][N] fp32 -> Wt [N][K] fp16
__global__ void k_wt(const float* __restrict__ W, _Float16* __restrict__ Wt, int K, int N) {
  int i = blockIdx.x * 256 + threadIdx.x;
  if (i >= K * N) return;
  int k = i / N, n = i % N;
  Wt[(size_t)n * K + k] = (_Float16)W[i];
}

// ---------------- MFMA fp16 GEMM: C[M,N] = A[M,K] * Bt[N,K]^T ----------------
// block = 256 (4 waves), each block covers 64 rows x all N cols.
template <int NCG, int K>
__launch_bounds__(256)
__global__ void k_gemm_mfma(const _Float16* __restrict__ A, const _Float16* __restrict__ Bt,
                            _Float16* __restrict__ C, int M) {
  constexpr int N = NCG * 16;
  int w = threadIdx.x >> 6, lane = threadIdx.x & 63;
  int r = lane & 15, kg = lane >> 4;
  int m0 = blockIdx.x * 64 + w * 16;
  f32x4 acc[NCG];
#pragma unroll
  for (int c = 0; c < NCG; ++c) acc[c] = (f32x4){0.f, 0.f, 0.f, 0.f};
  int mA = m0 + r; if (mA > M - 1) mA = M - 1;
  const _Float16* Arow = A + (size_t)mA * K + kg * 8;
#pragma unroll
  for (int k0 = 0; k0 < K; k0 += 32) {
    f16x8 a = *(const f16x8*)(Arow + k0);
#pragma unroll
    for (int c = 0; c < NCG; ++c) {
      f16x8 b = *(const f16x8*)&Bt[(size_t)(c * 16 + r) * K + k0 + kg * 8];
      acc[c] = __builtin_amdgcn_mfma_f32_16x16x32_f16(a, b, acc[c], 0, 0, 0);
    }
  }
  // C/D layout: col = lane&15, row = (lane>>4)*4 + j  [m89/m91-verified]
#pragma unroll
  for (int c = 0; c < NCG; ++c) {
#pragma unroll
    for (int j = 0; j < 4; ++j) {
      int m = m0 + kg * 4 + j;
      if (m < M) C[(size_t)m * N + c * 16 + r] = (_Float16)acc[c][j];
    }
  }
}

// ---------------- alpha projections ----------------
__launch_bounds__(256)
__global__ void k_alpha1(const _Float16* __restrict__ h1h, const float* __restrict__ a_s,
                         const float* __restrict__ a_d, float* __restrict__ as,
                         float* __restrict__ ad, int n) {
  int wave = threadIdx.x >> 6, lane = threadIdx.x & 63;
  int node = blockIdx.x * 4 + wave;
  if (node >= n) return;
  half4v hv = *(const half4v*)&h1h[(size_t)node * 256 + lane * 4];
  float4 sv = *(const float4*)&a_s[lane * 4];
  float4 dv = *(const float4*)&a_d[lane * 4];
  float h0 = (float)hv.x, h1 = (float)hv.y, h2 = (float)hv.z, h3 = (float)hv.w;
  float s = h0 * sv.x + h1 * sv.y + h2 * sv.z + h3 * sv.w;
  float d = h0 * dv.x + h1 * dv.y + h2 * dv.z + h3 * dv.w;
#pragma unroll
  for (int off = 1; off < 16; off <<= 1) { s += __shfl_xor(s, off); d += __shfl_xor(d, off); }
  if ((lane & 15) == 0) {
    as[node * 4 + (lane >> 4)] = s;
    ad[node * 4 + (lane >> 4)] = d;
  }
}

__launch_bounds__(256)
__global__ void k_alpha2(const _Float16* __restrict__ h2h, const float* __restrict__ a_s,
                         const float* __restrict__ a_d, float* __restrict__ as,
                         float* __restrict__ ad, int n) {
  int wave = threadIdx.x >> 6, lane = threadIdx.x & 63;
  int node = blockIdx.x * 4 + wave;
  if (node >= n) return;
  float hv = (float)h2h[(size_t)node * 64 + lane];
  float s = hv * a_s[lane];
  float d = hv * a_d[lane];
#pragma unroll
  for (int off = 1; off < 64; off <<= 1) { s += __shfl_xor(s, off); d += __shfl_xor(d, off); }
  if (lane == 0) { as[node] = s; ad[node] = d; }
}

// ---------------- edge weights (CSR slot order, coalesced) ----------------
__global__ void k_edgew1(const int* __restrict__ srcs, const int* __restrict__ dsts,
                         const float* __restrict__ as1, const float* __restrict__ ad1,
                         _Float16* __restrict__ w4h, int Et) {
  int i = blockIdx.x * 256 + threadIdx.x;
  if (i >= Et) return;
  int s = srcs[i], d = dsts[i];
  float4 a = *(const float4*)&as1[s * 4];
  float4 b = *(const float4*)&ad1[d * 4];
  half4v w;
  w.x = (_Float16)__expf(lrelu(a.x + b.x));
  w.y = (_Float16)__expf(lrelu(a.y + b.y));
  w.z = (_Float16)__expf(lrelu(a.z + b.z));
  w.w = (_Float16)__expf(lrelu(a.w + b.w));
  *(half4v*)&w4h[(size_t)i * 4] = w;
}

__global__ void k_edgew2(const int* __restrict__ srcs, const int* __restrict__ dsts,
                         const float* __restrict__ as2, const float* __restrict__ ad2,
                         _Float16* __restrict__ w2h, int Et) {
  int i = blockIdx.x * 256 + threadIdx.x;
  if (i >= Et) return;
  float z = as2[srcs[i]] + ad2[dsts[i]];
  w2h[i] = (_Float16)__expf(lrelu(z));
}

// ---------------- aggregation, layer 1: single-pass, unrolled x2 ----------------
__launch_bounds__(256)
__global__ void k_aggr1(const int* __restrict__ row_ptr, const int* __restrict__ srcs,
                        const _Float16* __restrict__ w4h, const _Float16* __restrict__ h1h,
                        const float* __restrict__ b1, _Float16* __restrict__ hrelu_h, int n) {
  int wave = threadIdx.x >> 6, lane = threadIdx.x & 63;
  int node = blockIdx.x * 4 + wave;
  if (node >= n) return;
  int beg = row_ptr[node], end = row_ptr[node + 1];
  int l32 = lane & 31, sub = lane >> 5;
  int ch0 = l32 * 8;       // 32 lanes x 8 ch = 256
  int myh = l32 >> 3;      // head 0..3
  const uint2* w4u = (const uint2*)w4h;
  float acc[8] = {};
  float dsum = 0.f;
  for (int i = beg; i < end; i += 4) {
    int idxA = i + sub;
    int idxB = i + 2 + sub;
    int sA = 0, sB = 0;
    float wA = 0.f, wB = 0.f;
    if (idxA < end) {
      sA = srcs[idxA];
      wA = pick_h4(w4u[idxA], myh);
    }
    if (idxB < end) {
      sB = srcs[idxB];
      wB = pick_h4(w4u[idxB], myh);
    }
    f16x8 hA = *(const f16x8*)&h1h[(size_t)sA * 256 + ch0];
    f16x8 hB = *(const f16x8*)&h1h[(size_t)sB * 256 + ch0];
    dsum += wA + wB;
#pragma unroll
    for (int j = 0; j < 8; ++j) acc[j] += wA * (float)hA[j];
#pragma unroll
    for (int j = 0; j < 8; ++j) acc[j] += wB * (float)hB[j];
  }
  dsum += __shfl_xor(dsum, 32);
  float inv = 1.0f / (dsum + 1e-16f);
#pragma unroll
  for (int j = 0; j < 8; ++j) acc[j] += __shfl_xor(acc[j], 32);
  if (sub == 0) {
    float4 bva = *(const float4*)&b1[ch0];
    float4 bvb = *(const float4*)&b1[ch0 + 4];
    float bb[8] = {bva.x, bva.y, bva.z, bva.w, bvb.x, bvb.y, bvb.z, bvb.w};
    f16x8 o;
#pragma unroll
    for (int j = 0; j < 8; ++j) o[j] = (_Float16)fmaxf(acc[j] * inv + bb[j], 0.f);
    *(f16x8*)&hrelu_h[(size_t)node * 256 + ch0] = o;
  }
}

// ---------------- aggregation, layer 2: single-pass, unrolled x2 ----------------
__launch_bounds__(256)
__global__ void k_aggr2(const int* __restrict__ row_ptr, const int* __restrict__ srcs,
                        const _Float16* __restrict__ w2h, const _Float16* __restrict__ h2h,
                        const float* __restrict__ b2, float* __restrict__ out, int n) {
  int wave = threadIdx.x >> 6, lane = threadIdx.x & 63;
  int node = blockIdx.x * 4 + wave;
  if (node >= n) return;
  int beg = row_ptr[node], end = row_ptr[node + 1];
  int l32 = lane & 31, sub = lane >> 5;
  int ch0 = l32 * 2;       // 32 lanes x 2 ch = 64
  float a0 = 0.f, a1 = 0.f, dsum = 0.f;
  for (int i = beg; i < end; i += 4) {
    int idxA = i + sub;
    int idxB = i + 2 + sub;
    int sA = 0, sB = 0;
    float wA = 0.f, wB = 0.f;
    if (idxA < end) { sA = srcs[idxA]; wA = (float)w2h[idxA]; }
    if (idxB < end) { sB = srcs[idxB]; wB = (float)w2h[idxB]; }
    half4v dummy;
    float2 hA, hB;
    {
      const _Float16* pA = &h2h[(size_t)sA * 64 + ch0];
      const _Float16* pB = &h2h[(size_t)sB * 64 + ch0];
      hA.x = (float)pA[0]; hA.y = (float)pA[1];
      hB.x = (float)pB[0]; hB.y = (float)pB[1];
    }
    (void)dummy;
    dsum += wA + wB;
    a0 += wA * hA.x + wB * hB.x;
    a1 += wA * hA.y + wB * hB.y;
  }
  dsum += __shfl_xor(dsum, 32);
  a0 += __shfl_xor(a0, 32);
  a1 += __shfl_xor(a1, 32);
  if (sub == 0) {
    float inv = 1.0f / (dsum + 1e-16f);
    float2 o;
    o.x = a0 * inv + b2[ch0];
    o.y = a1 * inv + b2[ch0 + 1];
    *(float2*)&out[(size_t)node * 64 + ch0] = o;
  }
}

// ---------------- launch ----------------
extern "C" void kernel_launch(void* const* d_in, const int* in_sizes, int n_in,
                              void* d_out, int out_size, void* d_ws, size_t ws_size,
                              hipStream_t stream) {
  const float* x    = (const float*)d_in[0];
  const int*   ei   = (const int*)d_in[1];
  const float* W1   = (const float*)d_in[2];
  const float* a_s1 = (const float*)d_in[3];
  const float* a_d1 = (const float*)d_in[4];
  const float* b1   = (const float*)d_in[5];
  const float* W2   = (const float*)d_in[6];
  const float* a_s2 = (const float*)d_in[7];
  const float* a_d2 = (const float*)d_in[8];
  const float* b2   = (const float*)d_in[9];
  float* out = (float*)d_out;

  const int n  = in_sizes[0] / IN_C;  // 50000
  const int E  = in_sizes[1] / 2;     // 1600000
  const int Et = E + n;
  const int* ei_src = ei;
  const int* ei_dst = ei + E;

  char* ws = (char*)d_ws;
  size_t off = 0;
  auto alloc = [&](size_t bytes) -> void* {
    void* p = ws + off;
    off = (off + bytes + 255) & ~(size_t)255;
    return p;
  };
  _Float16* xh      = (_Float16*)alloc((size_t)n * 128 * 2);
  _Float16* W1t     = (_Float16*)alloc((size_t)256 * 128 * 2);
  _Float16* W2t     = (_Float16*)alloc((size_t)64 * 256 * 2);
  _Float16* h1h     = (_Float16*)alloc((size_t)n * 256 * 2);
  _Float16* hrelu_h = (_Float16*)alloc((size_t)n * 256 * 2);
  _Float16* h2h     = (_Float16*)alloc((size_t)n * 64 * 2);
  float* as1        = (float*)alloc((size_t)n * 4 * 4);
  float* ad1        = (float*)alloc((size_t)n * 4 * 4);
  float* as2        = (float*)alloc((size_t)n * 4);
  float* ad2        = (float*)alloc((size_t)n * 4);
  int* cnt          = (int*)alloc((size_t)n * 4);
  int* loc          = (int*)alloc((size_t)n * 4);
  int* row_ptr      = (int*)alloc((size_t)(n + 1) * 4);
  int* fill         = (int*)alloc((size_t)n * 4);
  int* bsum         = (int*)alloc((size_t)256 * 4);
  int* srcs         = (int*)alloc((size_t)Et * 4);
  int* dsts         = (int*)alloc((size_t)Et * 4);
  _Float16* w4h     = (_Float16*)alloc((size_t)Et * 4 * 2);
  _Float16* w2h     = (_Float16*)alloc((size_t)Et * 2);

  int eb  = (Et + 255) / 256;
  int nb  = (n + 255) / 256;
  int nw  = (n + 3) / 4;
  int gx1 = (n + 63) / 64;

  // CSR build
  hipLaunchKernelGGL(k_zero_i32, dim3(nb), dim3(256), 0, stream, cnt, n);
  hipLaunchKernelGGL(k_count, dim3(eb), dim3(256), 0, stream, ei_dst, cnt, E, Et);
  hipLaunchKernelGGL(k_scan1, dim3(nb), dim3(256), 0, stream, cnt, loc, bsum, n);
  hipLaunchKernelGGL(k_scan2, dim3(1), dim3(256), 0, stream, bsum, nb, row_ptr + n);
  hipLaunchKernelGGL(k_scan3, dim3(nb), dim3(256), 0, stream, loc, bsum, row_ptr, fill, n);
  hipLaunchKernelGGL(k_scatter, dim3(eb), dim3(256), 0, stream, ei_src, ei_dst, fill, srcs, dsts, E, Et);

  // prep
  hipLaunchKernelGGL(k_xh, dim3((n * 128 / 4 + 255) / 256), dim3(256), 0, stream, x, xh, n * 128 / 4);
  hipLaunchKernelGGL(k_wt, dim3((128 * 256 + 255) / 256), dim3(256), 0, stream, W1, W1t, 128, 256);
  hipLaunchKernelGGL(k_wt, dim3((256 * 64 + 255) / 256), dim3(256), 0, stream, W2, W2t, 256, 64);

  // layer 1
  hipLaunchKernelGGL((k_gemm_mfma<16, 128>), dim3(gx1), dim3(256), 0, stream, xh, W1t, h1h, n);
  hipLaunchKernelGGL(k_alpha1, dim3(nw), dim3(256), 0, stream, h1h, a_s1, a_d1, as1, ad1, n);
  hipLaunchKernelGGL(k_edgew1, dim3(eb), dim3(256), 0, stream, srcs, dsts, as1, ad1, w4h, Et);
  hipLaunchKernelGGL(k_aggr1, dim3(nw), dim3(256), 0, stream, row_ptr, srcs, w4h, h1h, b1, hrelu_h, n);

  // layer 2
  hipLaunchKernelGGL((k_gemm_mfma<4, 256>), dim3(gx1), dim3(256), 0, stream, hrelu_h, W2t, h2h, n);
  hipLaunchKernelGGL(k_alpha2, dim3(nw), dim3(256), 0, stream, h2h, a_s2, a_d2, as2, ad2, n);
  hipLaunchKernelGGL(k_edgew2, dim3(eb), dim3(256), 0, stream, srcs, dsts, as2, ad2, w2h, Et);
  hipLaunchKernelGGL(k_aggr2, dim3(nw), dim3(256), 0, stream, row_ptr, srcs, w2h, h2h, b2, out, n);
}

// Round 4
// 417.459 us; speedup vs baseline: 1.8984x; 1.1824x over previous
//
#include <hip/hip_runtime.h>
#include <cstdint>
#include <cstddef>

#define IN_C 128

typedef _Float16 __attribute__((ext_vector_type(4))) half4v;
typedef _Float16 __attribute__((ext_vector_type(8))) f16x8;
typedef float    __attribute__((ext_vector_type(4))) f32x4;

static __device__ __forceinline__ float lrelu(float x) { return x > 0.f ? x : 0.2f * x; }

static __device__ __forceinline__ float h16_to_f(unsigned short u) {
  union { unsigned short u; _Float16 h; } c; c.u = u;
  return (float)c.h;
}
static __device__ __forceinline__ unsigned pack2h(float a, float b) {
  union { _Float16 h[2]; unsigned u; } c;
  c.h[0] = (_Float16)a; c.h[1] = (_Float16)b;
  return c.u;
}

// ---------------- CSR build ----------------
__global__ void k_zero_i32(int* __restrict__ p, int n) {
  int i = blockIdx.x * 256 + threadIdx.x;
  if (i < n) p[i] = 0;
}

__global__ void k_count(const int* __restrict__ ei_dst, int* __restrict__ cnt, int E, int Et) {
  int e = blockIdx.x * 256 + threadIdx.x;
  if (e >= Et) return;
  int d = (e < E) ? ei_dst[e] : (e - E);
  atomicAdd(&cnt[d], 1);
}

__global__ void k_scan1(const int* __restrict__ cnt, int* __restrict__ loc,
                        int* __restrict__ bsum, int n) {
  int tid = threadIdx.x;
  int i = blockIdx.x * 256 + tid;
  int v = (i < n) ? cnt[i] : 0;
  int lane = tid & 63, w = tid >> 6;
  int s = v;
#pragma unroll
  for (int off = 1; off < 64; off <<= 1) {
    int t = __shfl_up(s, off);
    if (lane >= off) s += t;
  }
  __shared__ int wt[4];
  if (lane == 63) wt[w] = s;
  __syncthreads();
  int add = 0;
#pragma unroll
  for (int k = 0; k < 4; ++k)
    if (k < w) add += wt[k];
  int incl = s + add;
  if (i < n) loc[i] = incl - v;
  if (tid == 255) bsum[blockIdx.x] = incl;
}

__global__ void k_scan2(int* __restrict__ bsum, int nb, int* __restrict__ total_out) {
  int tid = threadIdx.x;
  int v = (tid < nb) ? bsum[tid] : 0;
  int lane = tid & 63, w = tid >> 6;
  int s = v;
#pragma unroll
  for (int off = 1; off < 64; off <<= 1) {
    int t = __shfl_up(s, off);
    if (lane >= off) s += t;
  }
  __shared__ int wt[4];
  if (lane == 63) wt[w] = s;
  __syncthreads();
  int add = 0;
#pragma unroll
  for (int k = 0; k < 4; ++k)
    if (k < w) add += wt[k];
  int incl = s + add;
  if (tid < nb) bsum[tid] = incl - v;
  if (tid == 255) *total_out = incl;
}

__global__ void k_scan3(const int* __restrict__ loc, const int* __restrict__ bsum,
                        int* __restrict__ row_ptr, int* __restrict__ fill, int n) {
  int i = blockIdx.x * 256 + threadIdx.x;
  if (i < n) {
    int v = loc[i] + bsum[blockIdx.x];
    row_ptr[i] = v;
    fill[i] = v;
  }
}

// fused scatter: region-partitioned (r = blockIdx&7 -> XCD-local slot writes),
// computes layer-1 edge weights inline, writes one 16B record {s, d, w4(4xfp16)}.
__global__ void k_scatter_fused(const int* __restrict__ ei_src, const int* __restrict__ ei_dst,
                                int* __restrict__ fill,
                                const float* __restrict__ as1, const float* __restrict__ ad1,
                                uint4* __restrict__ recs, int E, int Et, int nPerReg, int n) {
  int r = blockIdx.x & 7;
  int e = (blockIdx.x >> 3) * 256 + threadIdx.x;
  if (e >= Et) return;
  int d = (e < E) ? ei_dst[e] : (e - E);
  int lo = r * nPerReg;
  int hi = (r == 7) ? n : lo + nPerReg;
  if (d < lo || d >= hi) return;
  int s = (e < E) ? ei_src[e] : d;
  int pos = atomicAdd(&fill[d], 1);
  float4 a = *(const float4*)&as1[s * 4];
  float4 b = *(const float4*)&ad1[d * 4];
  unsigned w01 = pack2h(__expf(lrelu(a.x + b.x)), __expf(lrelu(a.y + b.y)));
  unsigned w23 = pack2h(__expf(lrelu(a.z + b.z)), __expf(lrelu(a.w + b.w)));
  recs[pos] = make_uint4((unsigned)s, (unsigned)d, w01, w23);
}

// ---------------- prep ----------------
__global__ void k_xh(const float* __restrict__ x, _Float16* __restrict__ xh, int n4) {
  int i = blockIdx.x * 256 + threadIdx.x;
  if (i >= n4) return;
  float4 v = *(const float4*)&x[i * 4];
  half4v o;
  o.x = (_Float16)v.x; o.y = (_Float16)v.y; o.z = (_Float16)v.z; o.w = (_Float16)v.w;
  *(half4v*)&xh[i * 4] = o;
}

__global__ void k_wt(const float* __restrict__ W, _Float16* __restrict__ Wt, int K, int N) {
  int i = blockIdx.x * 256 + threadIdx.x;
  if (i >= K * N) return;
  int k = i / N, n = i % N;
  Wt[(size_t)n * K + k] = (_Float16)W[i];
}

// ---------------- MFMA fp16 GEMM: C[M,N] = A[M,K] * Bt[N,K]^T ----------------
template <int NCG, int K>
__launch_bounds__(256)
__global__ void k_gemm_mfma(const _Float16* __restrict__ A, const _Float16* __restrict__ Bt,
                            _Float16* __restrict__ C, int M) {
  constexpr int N = NCG * 16;
  int w = threadIdx.x >> 6, lane = threadIdx.x & 63;
  int r = lane & 15, kg = lane >> 4;
  int m0 = blockIdx.x * 64 + w * 16;
  f32x4 acc[NCG];
#pragma unroll
  for (int c = 0; c < NCG; ++c) acc[c] = (f32x4){0.f, 0.f, 0.f, 0.f};
  int mA = m0 + r; if (mA > M - 1) mA = M - 1;
  const _Float16* Arow = A + (size_t)mA * K + kg * 8;
#pragma unroll
  for (int k0 = 0; k0 < K; k0 += 32) {
    f16x8 a = *(const f16x8*)(Arow + k0);
#pragma unroll
    for (int c = 0; c < NCG; ++c) {
      f16x8 b = *(const f16x8*)&Bt[(size_t)(c * 16 + r) * K + k0 + kg * 8];
      acc[c] = __builtin_amdgcn_mfma_f32_16x16x32_f16(a, b, acc[c], 0, 0, 0);
    }
  }
#pragma unroll
  for (int c = 0; c < NCG; ++c) {
#pragma unroll
    for (int j = 0; j < 4; ++j) {
      int m = m0 + kg * 4 + j;
      if (m < M) C[(size_t)m * N + c * 16 + r] = (_Float16)acc[c][j];
    }
  }
}

// ---------------- alpha projections ----------------
__launch_bounds__(256)
__global__ void k_alpha1(const _Float16* __restrict__ h1h, const float* __restrict__ a_s,
                         const float* __restrict__ a_d, float* __restrict__ as,
                         float* __restrict__ ad, int n) {
  int wave = threadIdx.x >> 6, lane = threadIdx.x & 63;
  int node = blockIdx.x * 4 + wave;
  if (node >= n) return;
  half4v hv = *(const half4v*)&h1h[(size_t)node * 256 + lane * 4];
  float4 sv = *(const float4*)&a_s[lane * 4];
  float4 dv = *(const float4*)&a_d[lane * 4];
  float h0 = (float)hv.x, h1 = (float)hv.y, h2 = (float)hv.z, h3 = (float)hv.w;
  float s = h0 * sv.x + h1 * sv.y + h2 * sv.z + h3 * sv.w;
  float d = h0 * dv.x + h1 * dv.y + h2 * dv.z + h3 * dv.w;
#pragma unroll
  for (int off = 1; off < 16; off <<= 1) { s += __shfl_xor(s, off); d += __shfl_xor(d, off); }
  if ((lane & 15) == 0) {
    as[node * 4 + (lane >> 4)] = s;
    ad[node * 4 + (lane >> 4)] = d;
  }
}

__launch_bounds__(256)
__global__ void k_alpha2(const _Float16* __restrict__ h2h, const float* __restrict__ a_s,
                         const float* __restrict__ a_d, float* __restrict__ as,
                         float* __restrict__ ad, int n) {
  int wave = threadIdx.x >> 6, lane = threadIdx.x & 63;
  int node = blockIdx.x * 4 + wave;
  if (node >= n) return;
  float hv = (float)h2h[(size_t)node * 64 + lane];
  float s = hv * a_s[lane];
  float d = hv * a_d[lane];
#pragma unroll
  for (int off = 1; off < 64; off <<= 1) { s += __shfl_xor(s, off); d += __shfl_xor(d, off); }
  if (lane == 0) { as[node] = s; ad[node] = d; }
}

// layer-2 edge weights from records; emits packed {src, w(fp16)} per slot
__global__ void k_edgew2(const uint4* __restrict__ recs,
                         const float* __restrict__ as2, const float* __restrict__ ad2,
                         uint2* __restrict__ sw, int Et) {
  int i = blockIdx.x * 256 + threadIdx.x;
  if (i >= Et) return;
  uint4 rc = recs[i];
  int s = (int)rc.x, d = (int)rc.y;
  float z = as2[s] + ad2[d];
  uint2 o;
  o.x = rc.x;
  o.y = pack2h(__expf(lrelu(z)), 0.f) & 0xffffu;
  sw[i] = o;
}

// ---------------- aggregation, layer 1: 4 edges in flight ----------------
// 16-lane groups; group g handles edge i+g; lane covers 16 channels (32B).
__launch_bounds__(256)
__global__ void k_aggr1(const int* __restrict__ row_ptr, const uint4* __restrict__ recs,
                        const _Float16* __restrict__ h1h, const float* __restrict__ b1,
                        _Float16* __restrict__ hrelu_h, int n) {
  int wave = threadIdx.x >> 6, lane = threadIdx.x & 63;
  int node = blockIdx.x * 4 + wave;
  if (node >= n) return;
  int beg = row_ptr[node], end = row_ptr[node + 1];
  int g = lane >> 4, l16 = lane & 15;
  int ch0 = l16 * 16;      // 16 lanes x 16 ch = 256
  int myh = l16 >> 2;      // 4 lanes per head
  float acc[16] = {};
  float dsum = 0.f;
  for (int i = beg; i < end; i += 4) {
    int idx = i + g;
    int s = 0; float w = 0.f;
    if (idx < end) {
      uint4 rc = recs[idx];
      s = (int)rc.x;
      unsigned wp = (myh & 2) ? rc.w : rc.z;
      w = h16_to_f((myh & 1) ? (unsigned short)(wp >> 16) : (unsigned short)(wp & 0xffffu));
    }
    const _Float16* hp = &h1h[(size_t)s * 256 + ch0];
    f16x8 hA = *(const f16x8*)hp;
    f16x8 hB = *(const f16x8*)(hp + 8);
    dsum += w;
#pragma unroll
    for (int j = 0; j < 8; ++j) acc[j] += w * (float)hA[j];
#pragma unroll
    for (int j = 0; j < 8; ++j) acc[8 + j] += w * (float)hB[j];
  }
#pragma unroll
  for (int off = 16; off < 64; off <<= 1) {
    dsum += __shfl_xor(dsum, off);
#pragma unroll
    for (int j = 0; j < 16; ++j) acc[j] += __shfl_xor(acc[j], off);
  }
  if (g == 0) {
    float inv = 1.0f / (dsum + 1e-16f);
    f16x8 oA, oB;
#pragma unroll
    for (int j = 0; j < 8; ++j) {
      oA[j] = (_Float16)fmaxf(acc[j] * inv + b1[ch0 + j], 0.f);
      oB[j] = (_Float16)fmaxf(acc[8 + j] * inv + b1[ch0 + 8 + j], 0.f);
    }
    _Float16* op = &hrelu_h[(size_t)node * 256 + ch0];
    *(f16x8*)op = oA;
    *(f16x8*)(op + 8) = oB;
  }
}

// ---------------- aggregation, layer 2: 4 edges in flight ----------------
__launch_bounds__(256)
__global__ void k_aggr2(const int* __restrict__ row_ptr, const uint2* __restrict__ sw,
                        const _Float16* __restrict__ h2h, const float* __restrict__ b2,
                        float* __restrict__ out, int n) {
  int wave = threadIdx.x >> 6, lane = threadIdx.x & 63;
  int node = blockIdx.x * 4 + wave;
  if (node >= n) return;
  int beg = row_ptr[node], end = row_ptr[node + 1];
  int g = lane >> 4, l16 = lane & 15;
  int ch0 = l16 * 4;       // 16 lanes x 4 ch = 64
  float acc[4] = {};
  float dsum = 0.f;
  for (int i = beg; i < end; i += 4) {
    int idx = i + g;
    int s = 0; float w = 0.f;
    if (idx < end) {
      uint2 r = sw[idx];
      s = (int)r.x;
      w = h16_to_f((unsigned short)r.y);
    }
    half4v hv = *(const half4v*)&h2h[(size_t)s * 64 + ch0];
    dsum += w;
    acc[0] += w * (float)hv.x; acc[1] += w * (float)hv.y;
    acc[2] += w * (float)hv.z; acc[3] += w * (float)hv.w;
  }
#pragma unroll
  for (int off = 16; off < 64; off <<= 1) {
    dsum += __shfl_xor(dsum, off);
#pragma unroll
    for (int j = 0; j < 4; ++j) acc[j] += __shfl_xor(acc[j], off);
  }
  if (g == 0) {
    float inv = 1.0f / (dsum + 1e-16f);
    float4 o;
    o.x = acc[0] * inv + b2[ch0];
    o.y = acc[1] * inv + b2[ch0 + 1];
    o.z = acc[2] * inv + b2[ch0 + 2];
    o.w = acc[3] * inv + b2[ch0 + 3];
    *(float4*)&out[(size_t)node * 64 + ch0] = o;
  }
}

// ---------------- launch ----------------
extern "C" void kernel_launch(void* const* d_in, const int* in_sizes, int n_in,
                              void* d_out, int out_size, void* d_ws, size_t ws_size,
                              hipStream_t stream) {
  const float* x    = (const float*)d_in[0];
  const int*   ei   = (const int*)d_in[1];
  const float* W1   = (const float*)d_in[2];
  const float* a_s1 = (const float*)d_in[3];
  const float* a_d1 = (const float*)d_in[4];
  const float* b1   = (const float*)d_in[5];
  const float* W2   = (const float*)d_in[6];
  const float* a_s2 = (const float*)d_in[7];
  const float* a_d2 = (const float*)d_in[8];
  const float* b2   = (const float*)d_in[9];
  float* out = (float*)d_out;

  const int n  = in_sizes[0] / IN_C;  // 50000
  const int E  = in_sizes[1] / 2;     // 1600000
  const int Et = E + n;
  const int* ei_src = ei;
  const int* ei_dst = ei + E;

  char* ws = (char*)d_ws;
  size_t off = 0;
  auto alloc = [&](size_t bytes) -> void* {
    void* p = ws + off;
    off = (off + bytes + 255) & ~(size_t)255;
    return p;
  };
  _Float16* xh      = (_Float16*)alloc((size_t)n * 128 * 2);
  _Float16* W1t     = (_Float16*)alloc((size_t)256 * 128 * 2);
  _Float16* W2t     = (_Float16*)alloc((size_t)64 * 256 * 2);
  _Float16* h1h     = (_Float16*)alloc((size_t)n * 256 * 2);
  _Float16* hrelu_h = (_Float16*)alloc((size_t)n * 256 * 2);
  _Float16* h2h     = (_Float16*)alloc((size_t)n * 64 * 2);
  float* as1        = (float*)alloc((size_t)n * 4 * 4);
  float* ad1        = (float*)alloc((size_t)n * 4 * 4);
  float* as2        = (float*)alloc((size_t)n * 4);
  float* ad2        = (float*)alloc((size_t)n * 4);
  int* cnt          = (int*)alloc((size_t)n * 4);
  int* loc          = (int*)alloc((size_t)n * 4);
  int* row_ptr      = (int*)alloc((size_t)(n + 1) * 4);
  int* fill         = (int*)alloc((size_t)n * 4);
  int* bsum         = (int*)alloc((size_t)256 * 4);
  uint4* recs       = (uint4*)alloc((size_t)Et * 16);
  uint2* sw2        = (uint2*)alloc((size_t)Et * 8);

  int eb  = (Et + 255) / 256;
  int nb  = (n + 255) / 256;
  int nw  = (n + 3) / 4;
  int gx1 = (n + 63) / 64;
  int nPerReg = (n + 7) / 8;

  // CSR count + scan (independent of GEMM)
  hipLaunchKernelGGL(k_zero_i32, dim3(nb), dim3(256), 0, stream, cnt, n);
  hipLaunchKernelGGL(k_count, dim3(eb), dim3(256), 0, stream, ei_dst, cnt, E, Et);
  hipLaunchKernelGGL(k_scan1, dim3(nb), dim3(256), 0, stream, cnt, loc, bsum, n);
  hipLaunchKernelGGL(k_scan2, dim3(1), dim3(256), 0, stream, bsum, nb, row_ptr + n);
  hipLaunchKernelGGL(k_scan3, dim3(nb), dim3(256), 0, stream, loc, bsum, row_ptr, fill, n);

  // prep + layer-1 GEMM + alpha
  hipLaunchKernelGGL(k_xh, dim3((n * 128 / 4 + 255) / 256), dim3(256), 0, stream, x, xh, n * 128 / 4);
  hipLaunchKernelGGL(k_wt, dim3((128 * 256 + 255) / 256), dim3(256), 0, stream, W1, W1t, 128, 256);
  hipLaunchKernelGGL(k_wt, dim3((256 * 64 + 255) / 256), dim3(256), 0, stream, W2, W2t, 256, 64);
  hipLaunchKernelGGL((k_gemm_mfma<16, 128>), dim3(gx1), dim3(256), 0, stream, xh, W1t, h1h, n);
  hipLaunchKernelGGL(k_alpha1, dim3(nw), dim3(256), 0, stream, h1h, a_s1, a_d1, as1, ad1, n);

  // fused region-partitioned scatter (weights inline)
  hipLaunchKernelGGL(k_scatter_fused, dim3(eb * 8), dim3(256), 0, stream,
                     ei_src, ei_dst, fill, as1, ad1, recs, E, Et, nPerReg, n);

  // layer-1 aggregation
  hipLaunchKernelGGL(k_aggr1, dim3(nw), dim3(256), 0, stream, row_ptr, recs, h1h, b1, hrelu_h, n);

  // layer 2
  hipLaunchKernelGGL((k_gemm_mfma<4, 256>), dim3(gx1), dim3(256), 0, stream, hrelu_h, W2t, h2h, n);
  hipLaunchKernelGGL(k_alpha2, dim3(nw), dim3(256), 0, stream, h2h, a_s2, a_d2, as2, ad2, n);
  hipLaunchKernelGGL(k_edgew2, dim3(eb), dim3(256), 0, stream, recs, as2, ad2, sw2, Et);
  hipLaunchKernelGGL(k_aggr2, dim3(nw), dim3(256), 0, stream, row_ptr, sw2, h2h, b2, out, n);
}

// Round 5
// 402.342 us; speedup vs baseline: 1.9697x; 1.0376x over previous
//
#include <hip/hip_runtime.h>
#include <cstdint>
#include <cstddef>

#define IN_C 128

typedef _Float16 __attribute__((ext_vector_type(4))) half4v;
typedef _Float16 __attribute__((ext_vector_type(8))) f16x8;
typedef float    __attribute__((ext_vector_type(4))) f32x4;

static __device__ __forceinline__ float lrelu(float x) { return x > 0.f ? x : 0.2f * x; }

static __device__ __forceinline__ float h16_to_f(unsigned short u) {
  union { unsigned short u; _Float16 h; } c; c.u = u;
  return (float)c.h;
}
static __device__ __forceinline__ unsigned pack2h(float a, float b) {
  union { _Float16 h[2]; unsigned u; } c;
  c.h[0] = (_Float16)a; c.h[1] = (_Float16)b;
  return c.u;
}

// ---------------- CSR build ----------------
__global__ void k_zero_i32(int* __restrict__ p, int n) {
  int i = blockIdx.x * 256 + threadIdx.x;
  if (i < n) p[i] = 0;
}

__global__ void k_count(const int* __restrict__ ei_dst, int* __restrict__ cnt, int E, int Et) {
  int e = blockIdx.x * 256 + threadIdx.x;
  if (e >= Et) return;
  int d = (e < E) ? ei_dst[e] : (e - E);
  atomicAdd(&cnt[d], 1);
}

__global__ void k_scan1(const int* __restrict__ cnt, int* __restrict__ loc,
                        int* __restrict__ bsum, int n) {
  int tid = threadIdx.x;
  int i = blockIdx.x * 256 + tid;
  int v = (i < n) ? cnt[i] : 0;
  int lane = tid & 63, w = tid >> 6;
  int s = v;
#pragma unroll
  for (int off = 1; off < 64; off <<= 1) {
    int t = __shfl_up(s, off);
    if (lane >= off) s += t;
  }
  __shared__ int wt[4];
  if (lane == 63) wt[w] = s;
  __syncthreads();
  int add = 0;
#pragma unroll
  for (int k = 0; k < 4; ++k)
    if (k < w) add += wt[k];
  int incl = s + add;
  if (i < n) loc[i] = incl - v;
  if (tid == 255) bsum[blockIdx.x] = incl;
}

// merged scan2+scan3: every block redundantly reduces bsum (nb<=~256 values)
__global__ void k_scan3b(const int* __restrict__ loc, const int* __restrict__ bsum,
                         int* __restrict__ row_ptr, int* __restrict__ fill, int n, int nb) {
  int tid = threadIdx.x, b = blockIdx.x;
  int lane = tid & 63, w = tid >> 6;
  int p = 0, t = 0;
  for (int k = tid; k < nb; k += 256) {
    int v = bsum[k];
    t += v;
    if (k < b) p += v;
  }
#pragma unroll
  for (int off = 1; off < 64; off <<= 1) {
    p += __shfl_xor(p, off);
    t += __shfl_xor(t, off);
  }
  __shared__ int sp_[4], st_[4];
  if (lane == 0) { sp_[w] = p; st_[w] = t; }
  __syncthreads();
  p = sp_[0] + sp_[1] + sp_[2] + sp_[3];
  t = st_[0] + st_[1] + st_[2] + st_[3];
  int i = b * 256 + tid;
  if (i < n) {
    int v = loc[i] + p;
    row_ptr[i] = v;
    fill[i] = v;
  }
  if (b == 0 && tid == 0) row_ptr[n] = t;
}

// fused scatter: region-partitioned (r = blockIdx&7 -> XCD-local slot writes),
// computes layer-1 edge weights inline, writes one 16B record {s, d, w4(4xfp16)}.
__global__ void k_scatter_fused(const int* __restrict__ ei_src, const int* __restrict__ ei_dst,
                                int* __restrict__ fill,
                                const float* __restrict__ as1, const float* __restrict__ ad1,
                                uint4* __restrict__ recs, int E, int Et, int nPerReg, int n) {
  int r = blockIdx.x & 7;
  int e = (blockIdx.x >> 3) * 256 + threadIdx.x;
  if (e >= Et) return;
  int d = (e < E) ? ei_dst[e] : (e - E);
  int lo = r * nPerReg;
  int hi = (r == 7) ? n : lo + nPerReg;
  if (d < lo || d >= hi) return;
  int s = (e < E) ? ei_src[e] : d;
  int pos = atomicAdd(&fill[d], 1);
  float4 a = *(const float4*)&as1[s * 4];
  float4 b = *(const float4*)&ad1[d * 4];
  unsigned w01 = pack2h(__expf(lrelu(a.x + b.x)), __expf(lrelu(a.y + b.y)));
  unsigned w23 = pack2h(__expf(lrelu(a.z + b.z)), __expf(lrelu(a.w + b.w)));
  recs[pos] = make_uint4((unsigned)s, (unsigned)d, w01, w23);
}

// ---------------- prep ----------------
__global__ void k_xh(const float* __restrict__ x, _Float16* __restrict__ xh, int n4) {
  int i = blockIdx.x * 256 + threadIdx.x;
  if (i >= n4) return;
  float4 v = *(const float4*)&x[i * 4];
  half4v o;
  o.x = (_Float16)v.x; o.y = (_Float16)v.y; o.z = (_Float16)v.z; o.w = (_Float16)v.w;
  *(half4v*)&xh[i * 4] = o;
}

// both weight transposes in one launch: W [K][N] fp32 -> Wt [N][K] fp16
__global__ void k_wts(const float* __restrict__ W1, const float* __restrict__ W2,
                      _Float16* __restrict__ W1t, _Float16* __restrict__ W2t) {
  int i = blockIdx.x * 256 + threadIdx.x;
  if (i < 128 * 256) {
    int k = i / 256, nn = i % 256;
    W1t[(size_t)nn * 128 + k] = (_Float16)W1[i];
  } else {
    int j = i - 128 * 256;
    if (j < 256 * 64) {
      int k = j / 64, nn = j % 64;
      W2t[(size_t)nn * 256 + k] = (_Float16)W2[j];
    }
  }
}

// ---------------- MFMA GEMM1 + fused alpha: h1 = xh*W1t^T, as1/ad1 per head ----------------
__launch_bounds__(256)
__global__ void k_gemm1_a(const _Float16* __restrict__ A, const _Float16* __restrict__ Bt,
                          const float* __restrict__ a_s, const float* __restrict__ a_d,
                          _Float16* __restrict__ C, float* __restrict__ as1,
                          float* __restrict__ ad1, int M) {
  int w = threadIdx.x >> 6, lane = threadIdx.x & 63;
  int r = lane & 15, kg = lane >> 4;
  int m0 = blockIdx.x * 64 + w * 16;
  f32x4 acc[16];
#pragma unroll
  for (int c = 0; c < 16; ++c) acc[c] = (f32x4){0.f, 0.f, 0.f, 0.f};
  int mA = m0 + r; if (mA > M - 1) mA = M - 1;
  const _Float16* Arow = A + (size_t)mA * 128 + kg * 8;
#pragma unroll
  for (int k0 = 0; k0 < 128; k0 += 32) {
    f16x8 a = *(const f16x8*)(Arow + k0);
#pragma unroll
    for (int c = 0; c < 16; ++c) {
      f16x8 b = *(const f16x8*)&Bt[(size_t)(c * 16 + r) * 128 + k0 + kg * 8];
      acc[c] = __builtin_amdgcn_mfma_f32_16x16x32_f16(a, b, acc[c], 0, 0, 0);
    }
  }
  // alpha partials: flat a-index of this lane's col in group c is c*16+r; head = c>>2
  float sp[4][4] = {}, dp[4][4] = {};
#pragma unroll
  for (int c = 0; c < 16; ++c) {
    float asv = a_s[c * 16 + r];
    float adv = a_d[c * 16 + r];
#pragma unroll
    for (int j = 0; j < 4; ++j) {
      float v = acc[c][j];
      sp[c >> 2][j] += v * asv;
      dp[c >> 2][j] += v * adv;
    }
  }
#pragma unroll
  for (int off = 1; off < 16; off <<= 1) {
#pragma unroll
    for (int h = 0; h < 4; ++h)
#pragma unroll
      for (int j = 0; j < 4; ++j) {
        sp[h][j] += __shfl_xor(sp[h][j], off);
        dp[h][j] += __shfl_xor(dp[h][j], off);
      }
  }
  // C write (C/D layout: col=lane&15, row=(lane>>4)*4+j)
#pragma unroll
  for (int c = 0; c < 16; ++c) {
#pragma unroll
    for (int j = 0; j < 4; ++j) {
      int m = m0 + kg * 4 + j;
      if (m < M) C[(size_t)m * 256 + c * 16 + r] = (_Float16)acc[c][j];
    }
  }
  if (r == 0) {
#pragma unroll
    for (int j = 0; j < 4; ++j) {
      int m = m0 + kg * 4 + j;
      if (m < M) {
#pragma unroll
        for (int h = 0; h < 4; ++h) {
          as1[m * 4 + h] = sp[h][j];
          ad1[m * 4 + h] = dp[h][j];
        }
      }
    }
  }
}

// ---------------- MFMA GEMM2 + fused alpha (1 head, 64 cols) ----------------
__launch_bounds__(256)
__global__ void k_gemm2_a(const _Float16* __restrict__ A, const _Float16* __restrict__ Bt,
                          const float* __restrict__ a_s, const float* __restrict__ a_d,
                          _Float16* __restrict__ C, float* __restrict__ as2,
                          float* __restrict__ ad2, int M) {
  int w = threadIdx.x >> 6, lane = threadIdx.x & 63;
  int r = lane & 15, kg = lane >> 4;
  int m0 = blockIdx.x * 64 + w * 16;
  f32x4 acc[4];
#pragma unroll
  for (int c = 0; c < 4; ++c) acc[c] = (f32x4){0.f, 0.f, 0.f, 0.f};
  int mA = m0 + r; if (mA > M - 1) mA = M - 1;
  const _Float16* Arow = A + (size_t)mA * 256 + kg * 8;
#pragma unroll
  for (int k0 = 0; k0 < 256; k0 += 32) {
    f16x8 a = *(const f16x8*)(Arow + k0);
#pragma unroll
    for (int c = 0; c < 4; ++c) {
      f16x8 b = *(const f16x8*)&Bt[(size_t)(c * 16 + r) * 256 + k0 + kg * 8];
      acc[c] = __builtin_amdgcn_mfma_f32_16x16x32_f16(a, b, acc[c], 0, 0, 0);
    }
  }
  float sp[4] = {}, dp[4] = {};
#pragma unroll
  for (int c = 0; c < 4; ++c) {
    float asv = a_s[c * 16 + r];
    float adv = a_d[c * 16 + r];
#pragma unroll
    for (int j = 0; j < 4; ++j) {
      float v = acc[c][j];
      sp[j] += v * asv;
      dp[j] += v * adv;
    }
  }
#pragma unroll
  for (int off = 1; off < 16; off <<= 1) {
#pragma unroll
    for (int j = 0; j < 4; ++j) {
      sp[j] += __shfl_xor(sp[j], off);
      dp[j] += __shfl_xor(dp[j], off);
    }
  }
#pragma unroll
  for (int c = 0; c < 4; ++c) {
#pragma unroll
    for (int j = 0; j < 4; ++j) {
      int m = m0 + kg * 4 + j;
      if (m < M) C[(size_t)m * 64 + c * 16 + r] = (_Float16)acc[c][j];
    }
  }
  if (r == 0) {
#pragma unroll
    for (int j = 0; j < 4; ++j) {
      int m = m0 + kg * 4 + j;
      if (m < M) { as2[m] = sp[j]; ad2[m] = dp[j]; }
    }
  }
}

// ---------------- aggregation, layer 1: 8 edges in flight ----------------
__launch_bounds__(256)
__global__ void k_aggr1(const int* __restrict__ row_ptr, const uint4* __restrict__ recs,
                        const _Float16* __restrict__ h1h, const float* __restrict__ b1,
                        _Float16* __restrict__ hrelu_h, int n) {
  int wave = threadIdx.x >> 6, lane = threadIdx.x & 63;
  int node = blockIdx.x * 4 + wave;
  if (node >= n) return;
  int beg = row_ptr[node], end = row_ptr[node + 1];
  int g = lane >> 4, l16 = lane & 15;
  int ch0 = l16 * 16;      // 16 lanes x 16 ch = 256
  int myh = l16 >> 2;      // 4 lanes per head
  float acc[16] = {};
  float dsum = 0.f;
  for (int i = beg; i < end; i += 8) {
    int iA = i + g, iB = i + 4 + g;
    int sA = 0, sB = 0;
    float wA = 0.f, wB = 0.f;
    if (iA < end) {
      uint4 rc = recs[iA];
      sA = (int)rc.x;
      unsigned wp = (myh & 2) ? rc.w : rc.z;
      wA = h16_to_f((myh & 1) ? (unsigned short)(wp >> 16) : (unsigned short)(wp & 0xffffu));
    }
    if (iB < end) {
      uint4 rc = recs[iB];
      sB = (int)rc.x;
      unsigned wp = (myh & 2) ? rc.w : rc.z;
      wB = h16_to_f((myh & 1) ? (unsigned short)(wp >> 16) : (unsigned short)(wp & 0xffffu));
    }
    const _Float16* pA = &h1h[(size_t)sA * 256 + ch0];
    const _Float16* pB = &h1h[(size_t)sB * 256 + ch0];
    f16x8 a0 = *(const f16x8*)pA;
    f16x8 a1 = *(const f16x8*)(pA + 8);
    f16x8 c0 = *(const f16x8*)pB;
    f16x8 c1 = *(const f16x8*)(pB + 8);
    dsum += wA + wB;
#pragma unroll
    for (int j = 0; j < 8; ++j) acc[j] += wA * (float)a0[j];
#pragma unroll
    for (int j = 0; j < 8; ++j) acc[8 + j] += wA * (float)a1[j];
#pragma unroll
    for (int j = 0; j < 8; ++j) acc[j] += wB * (float)c0[j];
#pragma unroll
    for (int j = 0; j < 8; ++j) acc[8 + j] += wB * (float)c1[j];
  }
#pragma unroll
  for (int off = 16; off < 64; off <<= 1) {
    dsum += __shfl_xor(dsum, off);
#pragma unroll
    for (int j = 0; j < 16; ++j) acc[j] += __shfl_xor(acc[j], off);
  }
  if (g == 0) {
    float inv = 1.0f / (dsum + 1e-16f);
    f16x8 oA, oB;
#pragma unroll
    for (int j = 0; j < 8; ++j) {
      oA[j] = (_Float16)fmaxf(acc[j] * inv + b1[ch0 + j], 0.f);
      oB[j] = (_Float16)fmaxf(acc[8 + j] * inv + b1[ch0 + 8 + j], 0.f);
    }
    _Float16* op = &hrelu_h[(size_t)node * 256 + ch0];
    *(f16x8*)op = oA;
    *(f16x8*)(op + 8) = oB;
  }
}

// ---------------- aggregation, layer 2: fused weights, 8 edges in flight ----------------
__launch_bounds__(256)
__global__ void k_aggr2(const int* __restrict__ row_ptr, const uint4* __restrict__ recs,
                        const float* __restrict__ as2, const float* __restrict__ ad2,
                        const _Float16* __restrict__ h2h, const float* __restrict__ b2,
                        float* __restrict__ out, int n) {
  int wave = threadIdx.x >> 6, lane = threadIdx.x & 63;
  int node = blockIdx.x * 4 + wave;
  if (node >= n) return;
  int beg = row_ptr[node], end = row_ptr[node + 1];
  float adm = ad2[node];
  int g = lane >> 4, l16 = lane & 15;
  int ch0 = l16 * 4;       // 16 lanes x 4 ch = 64
  float acc[4] = {};
  float dsum = 0.f;
  for (int i = beg; i < end; i += 8) {
    int iA = i + g, iB = i + 4 + g;
    int sA = 0, sB = 0;
    float wA = 0.f, wB = 0.f;
    if (iA < end) {
      sA = (int)recs[iA].x;
      wA = __expf(lrelu(as2[sA] + adm));
    }
    if (iB < end) {
      sB = (int)recs[iB].x;
      wB = __expf(lrelu(as2[sB] + adm));
    }
    half4v hA = *(const half4v*)&h2h[(size_t)sA * 64 + ch0];
    half4v hB = *(const half4v*)&h2h[(size_t)sB * 64 + ch0];
    dsum += wA + wB;
    acc[0] += wA * (float)hA.x + wB * (float)hB.x;
    acc[1] += wA * (float)hA.y + wB * (float)hB.y;
    acc[2] += wA * (float)hA.z + wB * (float)hB.z;
    acc[3] += wA * (float)hA.w + wB * (float)hB.w;
  }
#pragma unroll
  for (int off = 16; off < 64; off <<= 1) {
    dsum += __shfl_xor(dsum, off);
#pragma unroll
    for (int j = 0; j < 4; ++j) acc[j] += __shfl_xor(acc[j], off);
  }
  if (g == 0) {
    float inv = 1.0f / (dsum + 1e-16f);
    float4 o;
    o.x = acc[0] * inv + b2[ch0];
    o.y = acc[1] * inv + b2[ch0 + 1];
    o.z = acc[2] * inv + b2[ch0 + 2];
    o.w = acc[3] * inv + b2[ch0 + 3];
    *(float4*)&out[(size_t)node * 64 + ch0] = o;
  }
}

// ---------------- launch ----------------
extern "C" void kernel_launch(void* const* d_in, const int* in_sizes, int n_in,
                              void* d_out, int out_size, void* d_ws, size_t ws_size,
                              hipStream_t stream) {
  const float* x    = (const float*)d_in[0];
  const int*   ei   = (const int*)d_in[1];
  const float* W1   = (const float*)d_in[2];
  const float* a_s1 = (const float*)d_in[3];
  const float* a_d1 = (const float*)d_in[4];
  const float* b1   = (const float*)d_in[5];
  const float* W2   = (const float*)d_in[6];
  const float* a_s2 = (const float*)d_in[7];
  const float* a_d2 = (const float*)d_in[8];
  const float* b2   = (const float*)d_in[9];
  float* out = (float*)d_out;

  const int n  = in_sizes[0] / IN_C;  // 50000
  const int E  = in_sizes[1] / 2;     // 1600000
  const int Et = E + n;
  const int* ei_src = ei;
  const int* ei_dst = ei + E;

  char* ws = (char*)d_ws;
  size_t off = 0;
  auto alloc = [&](size_t bytes) -> void* {
    void* p = ws + off;
    off = (off + bytes + 255) & ~(size_t)255;
    return p;
  };
  _Float16* xh      = (_Float16*)alloc((size_t)n * 128 * 2);
  _Float16* W1t     = (_Float16*)alloc((size_t)256 * 128 * 2);
  _Float16* W2t     = (_Float16*)alloc((size_t)64 * 256 * 2);
  _Float16* h1h     = (_Float16*)alloc((size_t)n * 256 * 2);
  _Float16* hrelu_h = (_Float16*)alloc((size_t)n * 256 * 2);
  _Float16* h2h     = (_Float16*)alloc((size_t)n * 64 * 2);
  float* as1        = (float*)alloc((size_t)n * 4 * 4);
  float* ad1        = (float*)alloc((size_t)n * 4 * 4);
  float* as2        = (float*)alloc((size_t)n * 4);
  float* ad2        = (float*)alloc((size_t)n * 4);
  int* cnt          = (int*)alloc((size_t)n * 4);
  int* loc          = (int*)alloc((size_t)n * 4);
  int* row_ptr      = (int*)alloc((size_t)(n + 1) * 4);
  int* fill         = (int*)alloc((size_t)n * 4);
  int* bsum         = (int*)alloc((size_t)256 * 4);
  uint4* recs       = (uint4*)alloc((size_t)Et * 16);

  int eb  = (Et + 255) / 256;
  int nb  = (n + 255) / 256;
  int nw  = (n + 3) / 4;
  int gx1 = (n + 63) / 64;
  int nPerReg = (n + 7) / 8;

  // CSR count + scan
  hipLaunchKernelGGL(k_zero_i32, dim3(nb), dim3(256), 0, stream, cnt, n);
  hipLaunchKernelGGL(k_count, dim3(eb), dim3(256), 0, stream, ei_dst, cnt, E, Et);
  hipLaunchKernelGGL(k_scan1, dim3(nb), dim3(256), 0, stream, cnt, loc, bsum, n);
  hipLaunchKernelGGL(k_scan3b, dim3(nb), dim3(256), 0, stream, loc, bsum, row_ptr, fill, n, nb);

  // prep
  hipLaunchKernelGGL(k_xh, dim3((n * 128 / 4 + 255) / 256), dim3(256), 0, stream, x, xh, n * 128 / 4);
  hipLaunchKernelGGL(k_wts, dim3((128 * 256 + 256 * 64 + 255) / 256), dim3(256), 0, stream,
                     W1, W2, W1t, W2t);

  // layer 1: GEMM(+alpha) -> scatter(+weights) -> aggregate
  hipLaunchKernelGGL(k_gemm1_a, dim3(gx1), dim3(256), 0, stream,
                     xh, W1t, a_s1, a_d1, h1h, as1, ad1, n);
  hipLaunchKernelGGL(k_scatter_fused, dim3(eb * 8), dim3(256), 0, stream,
                     ei_src, ei_dst, fill, as1, ad1, recs, E, Et, nPerReg, n);
  hipLaunchKernelGGL(k_aggr1, dim3(nw), dim3(256), 0, stream, row_ptr, recs, h1h, b1, hrelu_h, n);

  // layer 2: GEMM(+alpha) -> aggregate (weights fused)
  hipLaunchKernelGGL(k_gemm2_a, dim3(gx1), dim3(256), 0, stream,
                     hrelu_h, W2t, a_s2, a_d2, h2h, as2, ad2, n);
  hipLaunchKernelGGL(k_aggr2, dim3(nw), dim3(256), 0, stream,
                     row_ptr, recs, as2, ad2, h2h, b2, out, n);
}